// Round 1
// baseline (437.442 us; speedup 1.0000x reference)
//
#include <hip/hip_runtime.h>
#include <hip/hip_bf16.h>
#include <cstdint>

typedef __attribute__((ext_vector_type(8))) short bf16x8;
typedef __attribute__((ext_vector_type(4))) float f32x4;
using bf16 = __hip_bfloat16;

static __device__ __forceinline__ float tofloat(float x) { return x; }
static __device__ __forceinline__ float tofloat(bf16 x) { return __bfloat162float(x); }
static __device__ __forceinline__ void storeval(float* p, float v) { *p = v; }
static __device__ __forceinline__ void storeval(bf16* p, float v) { *p = __float2bfloat16(v); }

// ---------------- convert f32 -> bf16 (8 elems/thread) ----------------
__global__ __launch_bounds__(256) void convert_f32_bf16(const float* __restrict__ in,
                                                        bf16* __restrict__ out, long n) {
    long i = ((long)blockIdx.x * blockDim.x + threadIdx.x) * 8;
    if (i >= n) return;
    float4 a = *(const float4*)(in + i);
    float4 b = *(const float4*)(in + i + 4);
    bf16 t[8];
    t[0] = __float2bfloat16(a.x); t[1] = __float2bfloat16(a.y);
    t[2] = __float2bfloat16(a.z); t[3] = __float2bfloat16(a.w);
    t[4] = __float2bfloat16(b.x); t[5] = __float2bfloat16(b.y);
    t[6] = __float2bfloat16(b.z); t[7] = __float2bfloat16(b.w);
    *(uint4*)(out + i) = *(const uint4*)t;
}

// ---------------- transpose (+convert) to bf16, 32x32 tiles ----------------
template <typename SrcT>
__global__ __launch_bounds__(256) void transpose_to_bf16(const SrcT* __restrict__ src, long srcStride,
                                                         long srcBatch, bf16* __restrict__ dst,
                                                         long dstStride, long dstBatch) {
    __shared__ float tile[32][33];
    const SrcT* s = src + (long)blockIdx.z * srcBatch;
    bf16* d = dst + (long)blockIdx.z * dstBatch;
    long r0 = (long)blockIdx.y * 32, c0 = (long)blockIdx.x * 32;
    for (int i = threadIdx.y; i < 32; i += 8)
        tile[i][threadIdx.x] = tofloat(s[(r0 + i) * srcStride + c0 + threadIdx.x]);
    __syncthreads();
    for (int i = threadIdx.y; i < 32; i += 8)
        d[(c0 + i) * dstStride + r0 + threadIdx.x] = __float2bfloat16(tile[threadIdx.x][i]);
}

// ---------------- NT GEMM: C[M,N] = alpha * A[M,K] * B[N,K]^T (+ bias[N]) ----------------
// A,B bf16 row-major (K contiguous). 128x128 tile, BK=32, 4 waves (2x2), each wave 64x64.
#define BM 128
#define BN 128
#define BKG 32

template <typename OutT, bool BIAS>
__global__ __launch_bounds__(256) void gemm_nt(const bf16* __restrict__ A, long lda,
                                               const bf16* __restrict__ B, long ldb,
                                               OutT* __restrict__ C, long ldc,
                                               const float* __restrict__ bias, int K, float alpha) {
    __shared__ __align__(16) bf16 As[BM * BKG];
    __shared__ __align__(16) bf16 Bs[BN * BKG];

    const int tid = threadIdx.x;
    const int wave = tid >> 6;
    const int lane = tid & 63;
    const int l16 = lane & 15;
    const int lhi = lane >> 4;

    const long mtile = (long)blockIdx.y * BM;
    const long ntile = (long)blockIdx.x * BN;

    const int wr = (wave >> 1) * 64;
    const int wc = (wave & 1) * 64;

    f32x4 acc[4][4] = {};

    // staging: flat 16B-chunk index f = i*256 + tid; row = f>>2, kchunk = f&3
    const int rowS = tid >> 2;
    const int kcS = (tid & 3) * 8;
    const bf16* gA = A + (mtile + rowS) * lda + kcS;
    const bf16* gB = B + (ntile + rowS) * ldb + kcS;
    char* ldsA0 = (char*)As + (size_t)(wave * 64) * 16;
    char* ldsA1 = (char*)As + (size_t)(256 + wave * 64) * 16;
    char* ldsB0 = (char*)Bs + (size_t)(wave * 64) * 16;
    char* ldsB1 = (char*)Bs + (size_t)(256 + wave * 64) * 16;

    for (int k0 = 0; k0 < K; k0 += BKG) {
        __syncthreads();  // all waves done reading previous tile
        __builtin_amdgcn_global_load_lds(
            (const __attribute__((address_space(1))) unsigned int*)(gA + k0),
            (__attribute__((address_space(3))) unsigned int*)ldsA0, 16, 0, 0);
        __builtin_amdgcn_global_load_lds(
            (const __attribute__((address_space(1))) unsigned int*)(gA + 64 * lda + k0),
            (__attribute__((address_space(3))) unsigned int*)ldsA1, 16, 0, 0);
        __builtin_amdgcn_global_load_lds(
            (const __attribute__((address_space(1))) unsigned int*)(gB + k0),
            (__attribute__((address_space(3))) unsigned int*)ldsB0, 16, 0, 0);
        __builtin_amdgcn_global_load_lds(
            (const __attribute__((address_space(1))) unsigned int*)(gB + 64 * ldb + k0),
            (__attribute__((address_space(3))) unsigned int*)ldsB1, 16, 0, 0);
        __syncthreads();  // staging complete (compiler drains vmcnt before barrier)

        bf16x8 a[4], b[4];
#pragma unroll
        for (int m = 0; m < 4; ++m)
            a[m] = *(const bf16x8*)(As + (wr + m * 16 + l16) * BKG + lhi * 8);
#pragma unroll
        for (int n = 0; n < 4; ++n)
            b[n] = *(const bf16x8*)(Bs + (wc + n * 16 + l16) * BKG + lhi * 8);
#pragma unroll
        for (int m = 0; m < 4; ++m)
#pragma unroll
            for (int n = 0; n < 4; ++n)
                acc[m][n] = __builtin_amdgcn_mfma_f32_16x16x32_bf16(a[m], b[n], acc[m][n], 0, 0, 0);
    }

    // epilogue: C/D layout col = lane&15, row = (lane>>4)*4 + reg
#pragma unroll
    for (int n = 0; n < 4; ++n) {
        long col = ntile + wc + n * 16 + l16;
        float bv = BIAS ? bias[col] : 0.0f;
#pragma unroll
        for (int m = 0; m < 4; ++m) {
            long row = mtile + wr + m * 16 + lhi * 4;
#pragma unroll
            for (int r = 0; r < 4; ++r) {
                float v = acc[m][n][r] * alpha + bv;
                storeval(C + (row + r) * ldc + col, v);
            }
        }
    }
}

// ---------------- row softmax: fp32 [rows,2048] -> bf16 ----------------
__global__ __launch_bounds__(256) void softmax_rows(const float* __restrict__ S,
                                                    bf16* __restrict__ P, int ncols) {
    __shared__ float red[8];
    const long row = blockIdx.x;
    const float* srow = S + row * ncols;
    const int tid = threadIdx.x;
    float v[8];
    float4 x0 = ((const float4*)srow)[tid * 2];
    float4 x1 = ((const float4*)srow)[tid * 2 + 1];
    v[0] = x0.x; v[1] = x0.y; v[2] = x0.z; v[3] = x0.w;
    v[4] = x1.x; v[5] = x1.y; v[6] = x1.z; v[7] = x1.w;
    float m = -3.4e38f;
#pragma unroll
    for (int j = 0; j < 8; ++j) m = fmaxf(m, v[j]);
#pragma unroll
    for (int off = 32; off; off >>= 1) m = fmaxf(m, __shfl_xor(m, off));
    if ((tid & 63) == 0) red[tid >> 6] = m;
    __syncthreads();
    m = fmaxf(fmaxf(red[0], red[1]), fmaxf(red[2], red[3]));
    float s = 0.0f;
#pragma unroll
    for (int j = 0; j < 8; ++j) {
        v[j] = __expf(v[j] - m);
        s += v[j];
    }
#pragma unroll
    for (int off = 32; off; off >>= 1) s += __shfl_xor(s, off);
    if ((tid & 63) == 0) red[4 + (tid >> 6)] = s;
    __syncthreads();
    s = red[4] + red[5] + red[6] + red[7];
    float inv = 1.0f / s;
    bf16 o[8];
#pragma unroll
    for (int j = 0; j < 8; ++j) o[j] = __float2bfloat16(v[j] * inv);
    *(uint4*)(P + row * ncols + tid * 8) = *(const uint4*)o;
}

extern "C" void kernel_launch(void* const* d_in, const int* in_sizes, int n_in, void* d_out,
                              int out_size, void* d_ws, size_t ws_size, hipStream_t stream) {
    (void)in_sizes; (void)n_in; (void)out_size; (void)ws_size;
    const float* x = (const float*)d_in[0];
    const float* w_qkv = (const float*)d_in[1];
    const float* b_qkv = (const float*)d_in[2];
    const float* w_out = (const float*)d_in[3];
    const float* b_out = (const float*)d_in[4];
    float* out = (float*)d_out;

    const int B = 4, S = 2048, D = 1024;

    char* ws = (char*)d_ws;
    size_t off = 0;
    auto alloc = [&](size_t bytes) {
        char* p = ws + off;
        off += (bytes + 255) & ~(size_t)255;
        return p;
    };
    bf16* xb = (bf16*)alloc((size_t)B * S * D * 2);        // 16 MiB
    bf16* qkv = (bf16*)alloc((size_t)B * S * 3 * D * 2);   // 48 MiB
    bf16* wqkvT = (bf16*)alloc((size_t)3 * D * D * 2);     // 6 MiB
    bf16* woutT = (bf16*)alloc((size_t)D * D * 2);         // 2 MiB
    bf16* vt = (bf16*)alloc((size_t)B * D * S * 2);        // 16 MiB
    bf16* ao = (bf16*)alloc((size_t)B * S * D * 2);        // 16 MiB
    float* sc = (float*)alloc((size_t)S * S * 4);          // 16 MiB (per-batch reuse)
    bf16* attn = (bf16*)alloc((size_t)S * S * 2);          // 8 MiB (per-batch reuse)

    // 1. x -> bf16
    long nx = (long)B * S * D;
    convert_f32_bf16<<<(int)(nx / 8 / 256), 256, 0, stream>>>(x, xb, nx);

    // 2. weight transposes (+convert): wqkvT[n][k] = w_qkv[k][n]; woutT[n][k] = w_out[k][n]
    dim3 tb(32, 8);
    transpose_to_bf16<float><<<dim3(3 * D / 32, D / 32, 1), tb, 0, stream>>>(
        w_qkv, 3 * D, 0, wqkvT, D, 0);
    transpose_to_bf16<float><<<dim3(D / 32, D / 32, 1), tb, 0, stream>>>(
        w_out, D, 0, woutT, D, 0);

    // 3. QKV GEMM: qkv[M=8192, N=3072] = xb @ wqkvT^T + b_qkv
    gemm_nt<bf16, true><<<dim3(3 * D / BN, B * S / BM), 256, 0, stream>>>(
        xb, D, wqkvT, D, qkv, 3 * D, b_qkv, D, 1.0f);

    // 4. transpose V per batch: vt[b][d][t] = qkv[b*S+t][2D+d]
    transpose_to_bf16<bf16><<<dim3(D / 32, S / 32, B), tb, 0, stream>>>(
        qkv + 2 * D, 3 * D, (long)S * 3 * D, vt, S, (long)D * S);

    // 5. per-batch attention
    for (int b = 0; b < B; ++b) {
        const bf16* Qb = qkv + (size_t)b * S * 3 * D;
        const bf16* Kb = Qb + D;
        // scores = Q K^T / 32  (fp32)
        gemm_nt<float, false><<<dim3(S / BN, S / BM), 256, 0, stream>>>(
            Qb, 3 * D, Kb, 3 * D, sc, S, nullptr, D, 0.03125f);
        softmax_rows<<<S, 256, 0, stream>>>(sc, attn, S);
        // ao = attn @ vt^T  (NT: B[n=d][k=t] = vt[d][t])
        gemm_nt<bf16, false><<<dim3(D / BN, S / BM), 256, 0, stream>>>(
            attn, S, vt + (size_t)b * D * S, S, ao + (size_t)b * S * D, D, nullptr, S, 1.0f);
    }

    // 6. out proj: out[8192,1024] = ao @ woutT^T + b_out  (fp32 out)
    gemm_nt<float, true><<<dim3(D / BN, B * S / BM), 256, 0, stream>>>(
        ao, D, woutT, D, out, D, b_out, D, 1.0f);
}

// Round 2
// 252.066 us; speedup vs baseline: 1.7354x; 1.7354x over previous
//
#include <hip/hip_runtime.h>
#include <hip/hip_bf16.h>
#include <cstdint>

typedef __attribute__((ext_vector_type(8))) short bf16x8;
typedef __attribute__((ext_vector_type(4))) float f32x4;
using bf16 = __hip_bfloat16;

static __device__ __forceinline__ float tofloat(float x) { return x; }
static __device__ __forceinline__ float tofloat(bf16 x) { return __bfloat162float(x); }
static __device__ __forceinline__ void storeval(float* p, float v) { *p = v; }
static __device__ __forceinline__ void storeval(bf16* p, float v) { *p = __float2bfloat16(v); }

// ---------------- convert f32 -> bf16 (8 elems/thread) ----------------
__global__ __launch_bounds__(256) void convert_f32_bf16(const float* __restrict__ in,
                                                        bf16* __restrict__ out, long n) {
    long i = ((long)blockIdx.x * blockDim.x + threadIdx.x) * 8;
    if (i >= n) return;
    float4 a = *(const float4*)(in + i);
    float4 b = *(const float4*)(in + i + 4);
    bf16 t[8];
    t[0] = __float2bfloat16(a.x); t[1] = __float2bfloat16(a.y);
    t[2] = __float2bfloat16(a.z); t[3] = __float2bfloat16(a.w);
    t[4] = __float2bfloat16(b.x); t[5] = __float2bfloat16(b.y);
    t[6] = __float2bfloat16(b.z); t[7] = __float2bfloat16(b.w);
    *(uint4*)(out + i) = *(const uint4*)t;
}

// ---------------- transpose (+convert) to bf16, 32x32 tiles ----------------
template <typename SrcT>
__global__ __launch_bounds__(256) void transpose_to_bf16(const SrcT* __restrict__ src, long srcStride,
                                                         long srcBatch, bf16* __restrict__ dst,
                                                         long dstStride, long dstBatch) {
    __shared__ float tile[32][33];
    const SrcT* s = src + (long)blockIdx.z * srcBatch;
    bf16* d = dst + (long)blockIdx.z * dstBatch;
    long r0 = (long)blockIdx.y * 32, c0 = (long)blockIdx.x * 32;
    for (int i = threadIdx.y; i < 32; i += 8)
        tile[i][threadIdx.x] = tofloat(s[(r0 + i) * srcStride + c0 + threadIdx.x]);
    __syncthreads();
    for (int i = threadIdx.y; i < 32; i += 8)
        d[(c0 + i) * dstStride + r0 + threadIdx.x] = __float2bfloat16(tile[threadIdx.x][i]);
}

// ---------------- NT GEMM, 256x128 tile, BK=32, 8 waves, dbuf+prefetch, T2 swizzle ----------------
// C[M,N] = alpha * A[M,K] * B[N,K]^T (+ bias[N]).  A,B bf16 row-major (K contiguous).
#define BM 256
#define BN 128
#define BKT 32

#define MFMA_BF16 __builtin_amdgcn_mfma_f32_16x16x32_bf16

template <typename OutT, bool BIAS>
__global__ __launch_bounds__(512, 2) void gemm256(const bf16* __restrict__ A, long lda, long batchA,
                                                  const bf16* __restrict__ B, long ldb, long batchB,
                                                  OutT* __restrict__ C, long ldc, long batchC,
                                                  const float* __restrict__ bias, int K, float alpha) {
    // LDS: 2 bufs x (A 256x32 + B 128x32) bf16 = 48 KiB
    __shared__ __align__(16) bf16 lds[2][(BM + BN) * BKT];

    const int tid = threadIdx.x;
    const int wave = tid >> 6;
    const int lane = tid & 63;
    const int wm = wave >> 2;      // 0..1  -> 128-row half
    const int wn = wave & 3;       // 0..3  -> 32-col slice
    const int l16 = lane & 15;
    const int lhi = lane >> 4;

    const long mtile = (long)blockIdx.y * BM;
    const long ntile = (long)blockIdx.x * BN;
    A += (long)blockIdx.z * batchA;
    B += (long)blockIdx.z * batchB;
    C += (long)blockIdx.z * batchC;

    // swizzled k-chunk (16B) for fragment reads: phys = lhi ^ ((row>>1)&3); row parity dep = (l16>>1)&3
    const int kswz = (lhi ^ ((lane >> 1) & 3)) * 8;  // element offset within row

    // staging map: thread stages phys chunk f=tid -> (row=f>>2, kc_phys=f&3); fetch logical kc
    const int rowS = tid >> 2;                        // 0..127
    const int kclS = ((tid & 3) ^ ((tid >> 3) & 3)) * 8;  // logical k element offset
    const bf16* gA0 = A + (mtile + rowS) * lda + kclS;
    const bf16* gA1 = gA0 + 128 * lda;
    const bf16* gB0 = B + (ntile + rowS) * ldb + kclS;

    auto stageA = [&](int buf, int t) {
        const bf16* s0 = gA0 + t * BKT;
        const bf16* s1 = gA1 + t * BKT;
        bf16* d0 = &lds[buf][wave * 512];
        __builtin_amdgcn_global_load_lds((const __attribute__((address_space(1))) unsigned int*)s0,
                                         (__attribute__((address_space(3))) unsigned int*)d0, 16, 0, 0);
        __builtin_amdgcn_global_load_lds((const __attribute__((address_space(1))) unsigned int*)s1,
                                         (__attribute__((address_space(3))) unsigned int*)(d0 + 4096), 16, 0, 0);
    };
    auto stageB = [&](int buf, int t) {
        const bf16* s0 = gB0 + t * BKT;
        bf16* d0 = &lds[buf][BM * BKT + wave * 512];
        __builtin_amdgcn_global_load_lds((const __attribute__((address_space(1))) unsigned int*)s0,
                                         (__attribute__((address_space(3))) unsigned int*)d0, 16, 0, 0);
    };
    auto loadA = [&](int buf, int m) -> bf16x8 {
        return *(const bf16x8*)&lds[buf][(wm * 128 + m * 16 + l16) * BKT + kswz];
    };
    auto loadB = [&](int buf, int n) -> bf16x8 {
        return *(const bf16x8*)&lds[buf][BM * BKT + (wn * 32 + n * 16 + l16) * BKT + kswz];
    };

    f32x4 acc[8][2] = {};

    stageA(0, 0);
    stageB(0, 0);
    __syncthreads();

    const int NT = K / BKT;
    for (int t = 0; t < NT; ++t) {
        const int buf = t & 1;
        const bool pre = (t + 1 < NT);
        // ---- phase 0: compute M-half 0, prefetch next A ----
        if (pre) stageA(buf ^ 1, t + 1);
        bf16x8 b0 = loadB(buf, 0);
        bf16x8 b1 = loadB(buf, 1);
        bf16x8 a0 = loadA(buf, 0), a1 = loadA(buf, 1), a2 = loadA(buf, 2), a3 = loadA(buf, 3);
        __builtin_amdgcn_s_setprio(1);
        acc[0][0] = MFMA_BF16(a0, b0, acc[0][0], 0, 0, 0);
        acc[0][1] = MFMA_BF16(a0, b1, acc[0][1], 0, 0, 0);
        acc[1][0] = MFMA_BF16(a1, b0, acc[1][0], 0, 0, 0);
        acc[1][1] = MFMA_BF16(a1, b1, acc[1][1], 0, 0, 0);
        acc[2][0] = MFMA_BF16(a2, b0, acc[2][0], 0, 0, 0);
        acc[2][1] = MFMA_BF16(a2, b1, acc[2][1], 0, 0, 0);
        acc[3][0] = MFMA_BF16(a3, b0, acc[3][0], 0, 0, 0);
        acc[3][1] = MFMA_BF16(a3, b1, acc[3][1], 0, 0, 0);
        __builtin_amdgcn_s_setprio(0);
        __builtin_amdgcn_s_barrier();  // phase-lock waves (scheduling only)
        // ---- phase 1: compute M-half 1, prefetch next B ----
        if (pre) stageB(buf ^ 1, t + 1);
        a0 = loadA(buf, 4); a1 = loadA(buf, 5); a2 = loadA(buf, 6); a3 = loadA(buf, 7);
        __builtin_amdgcn_s_setprio(1);
        acc[4][0] = MFMA_BF16(a0, b0, acc[4][0], 0, 0, 0);
        acc[4][1] = MFMA_BF16(a0, b1, acc[4][1], 0, 0, 0);
        acc[5][0] = MFMA_BF16(a1, b0, acc[5][0], 0, 0, 0);
        acc[5][1] = MFMA_BF16(a1, b1, acc[5][1], 0, 0, 0);
        acc[6][0] = MFMA_BF16(a2, b0, acc[6][0], 0, 0, 0);
        acc[6][1] = MFMA_BF16(a2, b1, acc[6][1], 0, 0, 0);
        acc[7][0] = MFMA_BF16(a3, b0, acc[7][0], 0, 0, 0);
        acc[7][1] = MFMA_BF16(a3, b1, acc[7][1], 0, 0, 0);
        __builtin_amdgcn_s_setprio(0);
        __syncthreads();  // boundary: drains vmcnt (next tile staged) + joins waves
    }

    // epilogue: C/D layout col = lane&15, row = (lane>>4)*4 + reg
#pragma unroll
    for (int n = 0; n < 2; ++n) {
        long col = ntile + wn * 32 + n * 16 + l16;
        float bv = BIAS ? bias[col] : 0.0f;
#pragma unroll
        for (int m = 0; m < 8; ++m) {
            long row = mtile + wm * 128 + m * 16 + lhi * 4;
#pragma unroll
            for (int r = 0; r < 4; ++r) {
                float v = acc[m][n][r] * alpha + bv;
                storeval(&C[(row + r) * ldc + col], v);
            }
        }
    }
}

// ---------------- row softmax: fp32 [rows,2048] -> bf16 IN-PLACE over the row ----------------
__global__ __launch_bounds__(256) void softmax_rows(float* __restrict__ S, int ncols) {
    __shared__ float red[8];
    const long row = blockIdx.x;
    float* srow = S + row * ncols;
    const int tid = threadIdx.x;
    float v[8];
    float4 x0 = ((const float4*)srow)[tid * 2];
    float4 x1 = ((const float4*)srow)[tid * 2 + 1];
    v[0] = x0.x; v[1] = x0.y; v[2] = x0.z; v[3] = x0.w;
    v[4] = x1.x; v[5] = x1.y; v[6] = x1.z; v[7] = x1.w;
    float m = -3.4e38f;
#pragma unroll
    for (int j = 0; j < 8; ++j) m = fmaxf(m, v[j]);
#pragma unroll
    for (int off = 32; off; off >>= 1) m = fmaxf(m, __shfl_xor(m, off));
    if ((tid & 63) == 0) red[tid >> 6] = m;
    __syncthreads();   // also orders all loads before any in-place write
    m = fmaxf(fmaxf(red[0], red[1]), fmaxf(red[2], red[3]));
    float s = 0.0f;
#pragma unroll
    for (int j = 0; j < 8; ++j) {
        v[j] = __expf(v[j] - m);
        s += v[j];
    }
#pragma unroll
    for (int off = 32; off; off >>= 1) s += __shfl_xor(s, off);
    if ((tid & 63) == 0) red[4 + (tid >> 6)] = s;
    __syncthreads();
    s = red[4] + red[5] + red[6] + red[7];
    float inv = 1.0f / s;
    bf16 o[8];
#pragma unroll
    for (int j = 0; j < 8; ++j) o[j] = __float2bfloat16(v[j] * inv);
    // write bf16 row into the first half of this row's fp32 slot (PV reads with lda = 2*ncols)
    *(uint4*)((bf16*)srow + tid * 8) = *(const uint4*)o;
}

extern "C" void kernel_launch(void* const* d_in, const int* in_sizes, int n_in, void* d_out,
                              int out_size, void* d_ws, size_t ws_size, hipStream_t stream) {
    (void)in_sizes; (void)n_in; (void)out_size;
    const float* x = (const float*)d_in[0];
    const float* w_qkv = (const float*)d_in[1];
    const float* b_qkv = (const float*)d_in[2];
    const float* w_out = (const float*)d_in[3];
    const float* b_out = (const float*)d_in[4];
    float* out = (float*)d_out;

    const int B = 4, S = 2048, D = 1024;

    char* ws = (char*)d_ws;
    size_t off = 0;
    auto alloc = [&](size_t bytes) {
        char* p = ws + off;
        off += (bytes + 255) & ~(size_t)255;
        return p;
    };
    bf16* xb = (bf16*)alloc((size_t)B * S * D * 2);        // 16 MiB
    bf16* qkv = (bf16*)alloc((size_t)B * S * 3 * D * 2);   // 48 MiB
    bf16* wqkvT = (bf16*)alloc((size_t)3 * D * D * 2);     // 6 MiB
    bf16* woutT = (bf16*)alloc((size_t)D * D * 2);         // 2 MiB
    bf16* vt = (bf16*)alloc((size_t)B * D * S * 2);        // 16 MiB
    bf16* ao = (bf16*)alloc((size_t)B * S * D * 2);        // 16 MiB
    // scores: NB batches at a time, fp32, softmax'd in place to bf16
    size_t sc_bytes_full = (size_t)B * S * S * 4;          // 67 MiB
    int NB = (ws_size >= off + sc_bytes_full) ? B : 1;
    float* sc = (float*)alloc((size_t)NB * S * S * 4);

    // 1. x -> bf16
    long nx = (long)B * S * D;
    convert_f32_bf16<<<(int)(nx / 8 / 256), 256, 0, stream>>>(x, xb, nx);

    // 2. weight transposes (+convert)
    dim3 tb(32, 8);
    transpose_to_bf16<float><<<dim3(3 * D / 32, D / 32, 1), tb, 0, stream>>>(
        w_qkv, 3 * D, 0, wqkvT, D, 0);
    transpose_to_bf16<float><<<dim3(D / 32, D / 32, 1), tb, 0, stream>>>(
        w_out, D, 0, woutT, D, 0);

    // 3. QKV GEMM: [8192, 3072] = xb @ wqkvT^T + b_qkv
    gemm256<bf16, true><<<dim3(3 * D / BN, B * S / BM, 1), 512, 0, stream>>>(
        xb, D, 0, wqkvT, D, 0, qkv, 3 * D, 0, b_qkv, D, 1.0f);

    // 4. V transpose per batch: vt[b][d][t] = qkv[b*S+t][2D+d]
    transpose_to_bf16<bf16><<<dim3(D / 32, S / 32, B), tb, 0, stream>>>(
        qkv + 2 * D, 3 * D, (long)S * 3 * D, vt, S, (long)D * S);

    // 5. attention, NB batches per pass
    for (int b0 = 0; b0 < B; b0 += NB) {
        const bf16* Qb = qkv + (size_t)b0 * S * 3 * D;
        const bf16* Kb = Qb + D;
        // scores = Q K^T / 32 (fp32)
        gemm256<float, false><<<dim3(S / BN, S / BM, NB), 512, 0, stream>>>(
            Qb, 3 * D, (long)S * 3 * D, Kb, 3 * D, (long)S * 3 * D,
            sc, S, (long)S * S, nullptr, D, 0.03125f);
        // softmax in place (bf16 packed into each row's slot)
        softmax_rows<<<NB * S, 256, 0, stream>>>(sc, S);
        // ao = attn @ vt^T ; attn rows at stride 2S bf16
        gemm256<bf16, false><<<dim3(D / BN, S / BM, NB), 512, 0, stream>>>(
            (const bf16*)sc, 2 * S, (long)S * 2 * S,
            vt + (size_t)b0 * D * S, S, (long)D * S,
            ao + (size_t)b0 * S * D, D, (long)S * D, nullptr, S, 1.0f);
    }

    // 6. out proj: out[8192,1024] = ao @ woutT^T + b_out (fp32 out)
    gemm256<float, true><<<dim3(D / BN, B * S / BM, 1), 512, 0, stream>>>(
        ao, D, 0, woutT, D, 0, out, D, 0, b_out, D, 1.0f);
}

// Round 3
// 238.721 us; speedup vs baseline: 1.8324x; 1.0559x over previous
//
#include <hip/hip_runtime.h>
#include <hip/hip_bf16.h>
#include <cstdint>

typedef __attribute__((ext_vector_type(8))) short bf16x8;
typedef __attribute__((ext_vector_type(4))) float f32x4;
using bf16 = __hip_bfloat16;

static __device__ __forceinline__ float tofloat(float x) { return x; }
static __device__ __forceinline__ float tofloat(bf16 x) { return __bfloat162float(x); }
static __device__ __forceinline__ void storeval(float* p, float v) { *p = v; }
static __device__ __forceinline__ void storeval(bf16* p, float v) { *p = __float2bfloat16(v); }

#define MFMA_BF16 __builtin_amdgcn_mfma_f32_16x16x32_bf16

template <int N>
static __device__ __forceinline__ void vm_wait() {
    if constexpr (N == 0) asm volatile("s_waitcnt vmcnt(0)" ::: "memory");
    else if constexpr (N == 1) asm volatile("s_waitcnt vmcnt(1)" ::: "memory");
    else if constexpr (N == 2) asm volatile("s_waitcnt vmcnt(2)" ::: "memory");
    else if constexpr (N == 3) asm volatile("s_waitcnt vmcnt(3)" ::: "memory");
    else if constexpr (N == 4) asm volatile("s_waitcnt vmcnt(4)" ::: "memory");
}
static __device__ __forceinline__ void lgkm0() {
    asm volatile("s_waitcnt lgkmcnt(0)" ::: "memory");
    __builtin_amdgcn_sched_barrier(0);
}
static __device__ __forceinline__ void phase_bar() {
    __builtin_amdgcn_sched_barrier(0);
    __builtin_amdgcn_s_barrier();
    __builtin_amdgcn_sched_barrier(0);
}
static __device__ __forceinline__ void gl_lds(const bf16* src, char* dst) {
    __builtin_amdgcn_global_load_lds((const __attribute__((address_space(1))) unsigned int*)src,
                                     (__attribute__((address_space(3))) unsigned int*)dst, 16, 0, 0);
}

// ---------------- convert f32 -> bf16 ----------------
__global__ __launch_bounds__(256) void convert_f32_bf16(const float* __restrict__ in,
                                                        bf16* __restrict__ out, long n) {
    long i = ((long)blockIdx.x * blockDim.x + threadIdx.x) * 8;
    if (i >= n) return;
    float4 a = *(const float4*)(in + i);
    float4 b = *(const float4*)(in + i + 4);
    bf16 t[8];
    t[0] = __float2bfloat16(a.x); t[1] = __float2bfloat16(a.y);
    t[2] = __float2bfloat16(a.z); t[3] = __float2bfloat16(a.w);
    t[4] = __float2bfloat16(b.x); t[5] = __float2bfloat16(b.y);
    t[6] = __float2bfloat16(b.z); t[7] = __float2bfloat16(b.w);
    *(uint4*)(out + i) = *(const uint4*)t;
}

// ---------------- transpose (+convert) to bf16, 32x32 tiles ----------------
template <typename SrcT>
__global__ __launch_bounds__(256) void transpose_to_bf16(const SrcT* __restrict__ src, long srcStride,
                                                         long srcBatch, bf16* __restrict__ dst,
                                                         long dstStride, long dstBatch) {
    __shared__ float tile[32][33];
    const SrcT* s = src + (long)blockIdx.z * srcBatch;
    bf16* d = dst + (long)blockIdx.z * dstBatch;
    long r0 = (long)blockIdx.y * 32, c0 = (long)blockIdx.x * 32;
    for (int i = threadIdx.y; i < 32; i += 8)
        tile[i][threadIdx.x] = tofloat(s[(r0 + i) * srcStride + c0 + threadIdx.x]);
    __syncthreads();
    for (int i = threadIdx.y; i < 32; i += 8)
        d[(c0 + i) * dstStride + r0 + threadIdx.x] = __float2bfloat16(tile[threadIdx.x][i]);
}

// ============ 8-phase NT GEMM: C[M,N] = alpha*A[M,K]*B[N,K]^T (+bias[N]) ============
// BM=256 fixed, BNT in {128,256}. 8 waves. BK=64 split in two k-halves of 32.
// LDS: A regions 4x16KB @0, B regions 4x(BNT*64)B @65536. Double buffer x 2 k-halves.
// Swizzle: logical granule g (16B) of row r stored at phys gp = g ^ ((r>>1)&3).
template <typename OutT, bool BIAS, int BNT>
__global__ __launch_bounds__(512, 1) void gemm8p(
    const bf16* __restrict__ Ag, long lda, long batchA,
    const bf16* __restrict__ Bg, long ldb, long batchB,
    OutT* __restrict__ Cg, long ldc, long batchC,
    const float* __restrict__ bias, int K, float alpha,
    int TM, int TN, int ntiles) {
    constexpr int WN = (BNT == 256) ? 4 : 2;   // waves along N
    constexpr int MR = (BNT == 256) ? 8 : 4;   // per-wave 16-row frags (M)
    constexpr int BLD = BNT / 128;             // B loads/thread/half
    constexpr int VMC = 2 + BLD;               // counted wait
    extern __shared__ __align__(16) char smem[];

    const int tid = threadIdx.x;
    const int wave = tid >> 6, lane = tid & 63, l16 = lane & 15, lhi = lane >> 4;
    const int wm = wave / WN, wn = wave % WN;

    // staging map: slot p=tid(+512): r=p>>2, gp=p&3, logical g=gp^((r>>1)&3)
    const int rS = tid >> 2;
    const int gS = (tid & 3) ^ ((tid >> 3) & 3);
    const int wb = wave * 1024;  // per-wave LDS byte base within region

    // fragment read byte offsets (within a region)
    const int raB = wm * (MR * 16) + l16;
    const int aoff = raB * 64 + (lhi ^ ((raB >> 1) & 3)) * 16;
    const int rbB = wn * 64 + l16;
    const int boff = rbB * 64 + (lhi ^ ((rbB >> 1) & 3)) * 16;

    const int NT = K / 64;
    const int tpb = TM * TN;

    for (int tile = blockIdx.x; tile < ntiles; tile += gridDim.x) {
        const int z = tile / tpb;
        const int rr = tile % tpb;
        const long mtile = (long)(rr / TN) * 256;
        const long ntile = (long)(rr % TN) * BNT;

        const bf16* A = Ag + (long)z * batchA;
        const bf16* B = Bg + (long)z * batchB;
        OutT* C = Cg + (long)z * batchC;

        const bf16* sA = A + (mtile + rS) * lda + gS * 8;
        const bf16* sB = B + (ntile + rS) * ldb + gS * 8;

        auto stA = [&](int buf, int kh, int t) {
            const bf16* s = sA + t * 64 + kh * 32;
            char* d = smem + (buf * 2 + kh) * 16384 + wb;
            gl_lds(s, d);
            gl_lds(s + 128 * lda, d + 8192);
        };
        auto stB = [&](int buf, int kh, int t) {
            const bf16* s = sB + t * 64 + kh * 32;
            char* d = smem + 65536 + (buf * 2 + kh) * (BNT * 64) + wb;
            gl_lds(s, d);
            if constexpr (BLD == 2) gl_lds(s + 128 * ldb, d + 8192);
        };

        f32x4 acc[MR][4];
#pragma unroll
        for (int m = 0; m < MR; ++m)
#pragma unroll
            for (int n = 0; n < 4; ++n) acc[m][n] = f32x4{0.f, 0.f, 0.f, 0.f};

        // prologue: stage all 4 halves of tile 0 into buf0
        stA(0, 0, 0); stB(0, 0, 0); stA(0, 1, 0); stB(0, 1, 0);
        vm_wait<VMC>();   // klo halves landed (khi may be in flight)
        phase_bar();

        bf16x8 a[MR], b[4];
        for (int t = 0; t < NT; ++t) {
            const int buf = t & 1, nb = buf ^ 1;
            const bool pre = (t + 1 < NT);
            const char* Ar0 = smem + (buf * 2 + 0) * 16384 + aoff;
            const char* Ar1 = smem + (buf * 2 + 1) * 16384 + aoff;
            const char* Br0 = smem + 65536 + (buf * 2 + 0) * (BNT * 64) + boff;
            const char* Br1 = smem + 65536 + (buf * 2 + 1) * (BNT * 64) + boff;
            // ---- P1: stage A-klo(t+1); read A-klo + B-klo(n0,1); MFMA n0,1 @klo ----
            if (pre) stA(nb, 0, t + 1);
#pragma unroll
            for (int m = 0; m < MR; ++m) a[m] = *(const bf16x8*)(Ar0 + m * 1024);
            b[0] = *(const bf16x8*)(Br0);
            b[1] = *(const bf16x8*)(Br0 + 1024);
            phase_bar(); lgkm0();
            __builtin_amdgcn_s_setprio(1);
#pragma unroll
            for (int m = 0; m < MR; ++m) {
                acc[m][0] = MFMA_BF16(a[m], b[0], acc[m][0], 0, 0, 0);
                acc[m][1] = MFMA_BF16(a[m], b[1], acc[m][1], 0, 0, 0);
            }
            __builtin_amdgcn_s_setprio(0);
            phase_bar();
            // ---- P2: stage B-klo(t+1); read B-klo(n2,3); MFMA n2,3 @klo ----
            if (pre) stB(nb, 0, t + 1);
            b[2] = *(const bf16x8*)(Br0 + 2048);
            b[3] = *(const bf16x8*)(Br0 + 3072);
            phase_bar(); lgkm0();
            __builtin_amdgcn_s_setprio(1);
#pragma unroll
            for (int m = 0; m < MR; ++m) {
                acc[m][2] = MFMA_BF16(a[m], b[2], acc[m][2], 0, 0, 0);
                acc[m][3] = MFMA_BF16(a[m], b[3], acc[m][3], 0, 0, 0);
            }
            __builtin_amdgcn_s_setprio(0);
            if (pre) vm_wait<VMC>(); else vm_wait<0>();  // B-khi(t) landed
            phase_bar();
            // ---- P3: stage A-khi(t+1); read A-khi + B-khi(n0,1); MFMA n0,1 @khi ----
            if (pre) stA(nb, 1, t + 1);
#pragma unroll
            for (int m = 0; m < MR; ++m) a[m] = *(const bf16x8*)(Ar1 + m * 1024);
            b[0] = *(const bf16x8*)(Br1);
            b[1] = *(const bf16x8*)(Br1 + 1024);
            phase_bar(); lgkm0();
            __builtin_amdgcn_s_setprio(1);
#pragma unroll
            for (int m = 0; m < MR; ++m) {
                acc[m][0] = MFMA_BF16(a[m], b[0], acc[m][0], 0, 0, 0);
                acc[m][1] = MFMA_BF16(a[m], b[1], acc[m][1], 0, 0, 0);
            }
            __builtin_amdgcn_s_setprio(0);
            phase_bar();
            // ---- P4: stage B-khi(t+1); read B-khi(n2,3); MFMA n2,3 @khi ----
            if (pre) stB(nb, 1, t + 1);
            b[2] = *(const bf16x8*)(Br1 + 2048);
            b[3] = *(const bf16x8*)(Br1 + 3072);
            phase_bar(); lgkm0();
            __builtin_amdgcn_s_setprio(1);
#pragma unroll
            for (int m = 0; m < MR; ++m) {
                acc[m][2] = MFMA_BF16(a[m], b[2], acc[m][2], 0, 0, 0);
                acc[m][3] = MFMA_BF16(a[m], b[3], acc[m][3], 0, 0, 0);
            }
            __builtin_amdgcn_s_setprio(0);
            if (pre) vm_wait<VMC>();  // klo halves of t+1 landed
            phase_bar();
        }

        // epilogue: C/D layout col = lane&15, row = (lane>>4)*4 + reg
#pragma unroll
        for (int n = 0; n < 4; ++n) {
            long col = ntile + wn * 64 + n * 16 + l16;
            float bv = BIAS ? bias[col] : 0.0f;
#pragma unroll
            for (int m = 0; m < MR; ++m) {
                long row = mtile + wm * (MR * 16) + m * 16 + lhi * 4;
#pragma unroll
                for (int r2 = 0; r2 < 4; ++r2)
                    storeval(&C[(row + r2) * ldc + col], acc[m][n][r2] * alpha + bv);
            }
        }
    }
}

// ---------------- row softmax: fp32 [rows,2048] -> bf16 IN-PLACE ----------------
__global__ __launch_bounds__(256) void softmax_rows(float* __restrict__ S, int ncols) {
    __shared__ float red[8];
    const long row = blockIdx.x;
    float* srow = S + row * ncols;
    const int tid = threadIdx.x;
    float v[8];
    float4 x0 = ((const float4*)srow)[tid * 2];
    float4 x1 = ((const float4*)srow)[tid * 2 + 1];
    v[0] = x0.x; v[1] = x0.y; v[2] = x0.z; v[3] = x0.w;
    v[4] = x1.x; v[5] = x1.y; v[6] = x1.z; v[7] = x1.w;
    float m = -3.4e38f;
#pragma unroll
    for (int j = 0; j < 8; ++j) m = fmaxf(m, v[j]);
#pragma unroll
    for (int off = 32; off; off >>= 1) m = fmaxf(m, __shfl_xor(m, off));
    if ((tid & 63) == 0) red[tid >> 6] = m;
    __syncthreads();
    m = fmaxf(fmaxf(red[0], red[1]), fmaxf(red[2], red[3]));
    float s = 0.0f;
#pragma unroll
    for (int j = 0; j < 8; ++j) {
        v[j] = __expf(v[j] - m);
        s += v[j];
    }
#pragma unroll
    for (int off = 32; off; off >>= 1) s += __shfl_xor(s, off);
    if ((tid & 63) == 0) red[4 + (tid >> 6)] = s;
    __syncthreads();
    s = red[4] + red[5] + red[6] + red[7];
    float inv = 1.0f / s;
    bf16 o[8];
#pragma unroll
    for (int j = 0; j < 8; ++j) o[j] = __float2bfloat16(v[j] * inv);
    *(uint4*)((bf16*)srow + tid * 8) = *(const uint4*)o;
}

extern "C" void kernel_launch(void* const* d_in, const int* in_sizes, int n_in, void* d_out,
                              int out_size, void* d_ws, size_t ws_size, hipStream_t stream) {
    (void)in_sizes; (void)n_in; (void)out_size;
    const float* x = (const float*)d_in[0];
    const float* w_qkv = (const float*)d_in[1];
    const float* b_qkv = (const float*)d_in[2];
    const float* w_out = (const float*)d_in[3];
    const float* b_out = (const float*)d_in[4];
    float* out = (float*)d_out;

    const int B = 4, S = 2048, D = 1024;

    // raise dynamic-LDS limits (idempotent; harmless if it errors during capture
    // since the first uncaptured call already set it)
    {
        auto k1 = &gemm8p<bf16, true, 128>;
        auto k2 = &gemm8p<float, false, 256>;
        auto k3 = &gemm8p<bf16, false, 128>;
        auto k4 = &gemm8p<float, true, 128>;
        (void)hipFuncSetAttribute((const void*)k1, hipFuncAttributeMaxDynamicSharedMemorySize, 98304);
        (void)hipFuncSetAttribute((const void*)k2, hipFuncAttributeMaxDynamicSharedMemorySize, 131072);
        (void)hipFuncSetAttribute((const void*)k3, hipFuncAttributeMaxDynamicSharedMemorySize, 98304);
        (void)hipFuncSetAttribute((const void*)k4, hipFuncAttributeMaxDynamicSharedMemorySize, 98304);
    }

    char* ws = (char*)d_ws;
    size_t off = 0;
    auto alloc = [&](size_t bytes) {
        char* p = ws + off;
        off += (bytes + 255) & ~(size_t)255;
        return p;
    };
    bf16* xb = (bf16*)alloc((size_t)B * S * D * 2);
    bf16* qkv = (bf16*)alloc((size_t)B * S * 3 * D * 2);
    bf16* wqkvT = (bf16*)alloc((size_t)3 * D * D * 2);
    bf16* woutT = (bf16*)alloc((size_t)D * D * 2);
    bf16* vt = (bf16*)alloc((size_t)B * D * S * 2);
    bf16* ao = (bf16*)alloc((size_t)B * S * D * 2);
    size_t sc_bytes_full = (size_t)B * S * S * 4;
    int NB = (ws_size >= off + sc_bytes_full) ? B : 1;
    float* sc = (float*)alloc((size_t)NB * S * S * 4);

    // 1. x -> bf16
    long nx = (long)B * S * D;
    convert_f32_bf16<<<(int)(nx / 8 / 256), 256, 0, stream>>>(x, xb, nx);

    // 2. weight transposes (+convert)
    dim3 tb(32, 8);
    transpose_to_bf16<float><<<dim3(3 * D / 32, D / 32, 1), tb, 0, stream>>>(
        w_qkv, 3 * D, 0, wqkvT, D, 0);
    transpose_to_bf16<float><<<dim3(D / 32, D / 32, 1), tb, 0, stream>>>(
        w_out, D, 0, woutT, D, 0);

    // 3. QKV GEMM: [8192,3072] = xb @ wqkvT^T + b_qkv  (768 tiles of 256x128)
    gemm8p<bf16, true, 128><<<256, 512, 98304, stream>>>(
        xb, D, 0, wqkvT, D, 0, qkv, 3 * D, 0, b_qkv, D, 1.0f,
        B * S / 256, 3 * D / 128, (B * S / 256) * (3 * D / 128));

    // 4. V transpose per batch: vt[b][d][t] = qkv[b*S+t][2D+d]
    transpose_to_bf16<bf16><<<dim3(D / 32, S / 32, B), tb, 0, stream>>>(
        qkv + 2 * D, 3 * D, (long)S * 3 * D, vt, S, (long)D * S);

    // 5. attention
    for (int b0 = 0; b0 < B; b0 += NB) {
        const bf16* Qb = qkv + (size_t)b0 * S * 3 * D;
        const bf16* Kb = Qb + D;
        // scores = Q K^T / 32 (fp32), 256x256 tiles: 8x8 per batch
        {
            int TM = S / 256, TN = S / 256, nt = NB * TM * TN;
            gemm8p<float, false, 256><<<(nt < 256 ? nt : 256), 512, 131072, stream>>>(
                Qb, 3 * D, (long)S * 3 * D, Kb, 3 * D, (long)S * 3 * D,
                sc, S, (long)S * S, nullptr, D, 0.03125f, TM, TN, nt);
        }
        softmax_rows<<<NB * S, 256, 0, stream>>>(sc, S);
        // ao = attn @ vt^T : 256x128 tiles, 8x8 per batch
        {
            int TM = S / 256, TN = D / 128, nt = NB * TM * TN;
            gemm8p<bf16, false, 128><<<(nt < 256 ? nt : 256), 512, 98304, stream>>>(
                (const bf16*)sc, 2 * S, (long)S * 2 * S,
                vt + (size_t)b0 * D * S, S, (long)D * S,
                ao + (size_t)b0 * S * D, D, (long)S * D, nullptr, S, 1.0f, TM, TN, nt);
        }
    }

    // 6. out proj: out[8192,1024] = ao @ woutT^T + b_out (fp32 out), 256 tiles
    gemm8p<float, true, 128><<<256, 512, 98304, stream>>>(
        ao, D, 0, woutT, D, 0, out, D, 0, b_out, D, 1.0f,
        B * S / 256, D / 128, (B * S / 256) * (D / 128));
}